// Round 18
// baseline (627.225 us; speedup 1.0000x reference)
//
#include <hip/hip_runtime.h>
#include <math.h>

#define N_NODES 65536
#define NE      524288
#define DD      128
#define BGRAPH  128
#define NPG     512
#define RATIO_K 128
#define NHEAD   4
#define DHEAD   32

typedef short bf16x8 __attribute__((ext_vector_type(8)));
typedef float f32x4 __attribute__((ext_vector_type(4)));

union U8 { unsigned short u[8]; bf16x8 v; };
union U4x { unsigned q[4]; bf16x8 v; };

__device__ __forceinline__ unsigned short f2b(float f) {
  unsigned u = __float_as_uint(f);
  unsigned r = u + 0x7fffu + ((u >> 16) & 1u);   // RTNE
  return (unsigned short)(r >> 16);
}
__device__ __forceinline__ float b2f(unsigned short h) {
  return __uint_as_float(((unsigned)h) << 16);
}
__device__ __forceinline__ void split3t(float v, unsigned short& h, unsigned short& m, unsigned short& l) {
  unsigned u = __float_as_uint(v);
  h = (unsigned short)(u >> 16);
  float vm = v - __uint_as_float(u & 0xffff0000u);
  unsigned um = __float_as_uint(vm);
  m = (unsigned short)(um >> 16);
  float vl = vm - __uint_as_float(um & 0xffff0000u);
  l = (unsigned short)(__float_as_uint(vl) >> 16);
}

// ======================= graph preprocessing =======================

__global__ void count_kernel(const int* __restrict__ dst, int* __restrict__ cnt) {
  int e = blockIdx.x * 256 + threadIdx.x;
  if (e < NE) atomicAdd(&cnt[dst[e]], 1);
}

__global__ void dinv_kernel(const int* __restrict__ cnt, float* __restrict__ dinv) {
  int i = blockIdx.x * 256 + threadIdx.x;
  if (i < N_NODES) dinv[i] = rsqrtf((float)cnt[i] + 1.0f);
}

__global__ __launch_bounds__(512) void scan_kernel2(const int* __restrict__ cnt, int* __restrict__ rp) {
  __shared__ int part[512];
  int g = blockIdx.x, t = threadIdx.x;
  int v = cnt[g * 512 + t];
  part[t] = v;
  __syncthreads();
  for (int off = 1; off < 512; off <<= 1) {
    int u = (t >= off) ? part[t - off] : 0;
    __syncthreads();
    part[t] += u;
    __syncthreads();
  }
  rp[g * 512 + t] = g * 4096 + part[t] - v;   // exclusive
  if (g == BGRAPH - 1 && t == 511) rp[N_NODES] = NE;
}

__global__ void scatter_kernel(const int* __restrict__ edge, const int* __restrict__ rp,
                               int* __restrict__ fill, const float* __restrict__ dinv,
                               int* __restrict__ col, float* __restrict__ wgt) {
  int e = blockIdx.x * 256 + threadIdx.x;
  if (e >= NE) return;
  int s = edge[e];
  int d = edge[NE + e];
  int p = rp[d] + atomicAdd(&fill[d], 1);
  col[p] = s;
  wgt[p] = dinv[s] * dinv[d];
}

// ======================= weight prep (all 14 mats in one launch) =======================
struct WPtrs { const float* p[14]; };

__global__ void wprep_all(WPtrs wp, unsigned short* __restrict__ dstBase) {
  int mat = blockIdx.y;
  int idx = blockIdx.x * 256 + threadIdx.x;
  const float* __restrict__ W = wp.p[mat];
  unsigned short* __restrict__ dst = dstBase + (size_t)mat * 49152;
  int k = idx >> 7, n = idx & 127;
  float v = W[k * 128 + n];
  unsigned short h, m, l;
  split3t(v, h, m, l);
  dst[n * 128 + k] = h;
  dst[16384 + n * 128 + k] = m;
  dst[32768 + n * 128 + k] = l;
}

// ======================= MFMA GEMM v11: h+m planes in LDS, l-plane direct from L2 =======================
#define WROW 36

template<int NW, bool RELU, bool RES, bool DUAL, bool DOT, bool GATHER, bool RDOUT>
__global__ __launch_bounds__(256, 2) void mfma_gemm8(
    const float* __restrict__ A,
    const unsigned short* __restrict__ Wt,
    const float* __restrict__ bias, const float* __restrict__ bias2,
    const float* __restrict__ res,
    float* __restrict__ out, float* __restrict__ out2,
    const float* __restrict__ dw1, const float* __restrict__ dw2,
    float* __restrict__ t1g, float* __restrict__ t2g,
    const int* __restrict__ tidxp, const float* __restrict__ tvalp,
    const float* __restrict__ ro_w, float* __restrict__ xg) {
  __shared__ unsigned short Wlds[NW * 2 * 64 * WROW];
  int tid = threadIdx.x;
  int wave = tid >> 6, lane = tid & 63;
  int c16 = lane & 15, kg = lane >> 4;
  int wrow = (wave >> 1) * 32;
  int wcol = (wave & 1) * 32;
  size_t row0 = (size_t)blockIdx.y * 64 + wrow;
  int n0 = blockIdx.x * 64;

  // A row pointers (with optional pooled-gather indirection), hoisted
  const float* arow[2];
  float ascale[2];
  #pragma unroll
  for (int mi = 0; mi < 2; ++mi) {
    size_t gr = row0 + mi * 16 + c16;
    if (GATHER) {
      int b = (int)(gr >> 7);
      int node = tidxp[gr];
      arow[mi] = A + ((size_t)b * NPG + node) * DD;
      ascale[mi] = tanhf(tvalp[gr]);
    } else {
      arow[mi] = A + gr * DD;
      ascale[mi] = 1.f;
    }
  }

  f32x4 acc[NW][2][2];
  #pragma unroll
  for (int m = 0; m < NW; ++m)
    #pragma unroll
    for (int mi = 0; mi < 2; ++mi)
      #pragma unroll
      for (int ni = 0; ni < 2; ++ni) acc[m][mi][ni] = (f32x4){0.f, 0.f, 0.f, 0.f};

  for (int ks = 0; ks < 4; ++ks) {
    if (ks) __syncthreads();
    // stage h + m planes only (l loaded direct from global/L2)
    #pragma unroll
    for (int i = 0; i < NW * 2; ++i) {
      int c = tid + i * 256;
      int u4 = c & 3;
      int n = (c >> 2) & 63;
      int mp = c >> 8;                 // mat*2 + plane(h/m)
      int mat = mp >> 1, p = mp & 1;
      *(uint4*)&Wlds[(mp * 64 + n) * WROW + u4 * 8] =
          *(const uint4*)&Wt[(size_t)mat * 49152 + (size_t)p * 16384 +
                             (n0 + n) * 128 + ks * 32 + u4 * 8];
    }
    __syncthreads();

    bf16x8 a[2][3];
    #pragma unroll
    for (int mi = 0; mi < 2; ++mi) {
      const float* ap = arow[mi] + ks * 32 + kg * 8;
      float4 f0 = *(const float4*)ap;
      float4 f1 = *(const float4*)(ap + 4);
      float f[8] = {f0.x, f0.y, f0.z, f0.w, f1.x, f1.y, f1.z, f1.w};
      if (GATHER) {
        #pragma unroll
        for (int j = 0; j < 8; ++j) f[j] *= ascale[mi];
      }
      U4x hh, mm, ll;
      #pragma unroll
      for (int p = 0; p < 4; ++p) {
        float v0 = f[2 * p], v1 = f[2 * p + 1];
        unsigned u0 = __float_as_uint(v0), u1 = __float_as_uint(v1);
        unsigned u1m = u1 & 0xffff0000u;
        hh.q[p] = (u0 >> 16) | u1m;
        float m0 = v0 - __uint_as_float(u0 & 0xffff0000u);
        float m1 = v1 - __uint_as_float(u1m);
        unsigned w0 = __float_as_uint(m0), w1 = __float_as_uint(m1);
        unsigned w1m = w1 & 0xffff0000u;
        mm.q[p] = (w0 >> 16) | w1m;
        float l0 = m0 - __uint_as_float(w0 & 0xffff0000u);
        float l1 = m1 - __uint_as_float(w1m);
        ll.q[p] = (__float_as_uint(l0) >> 16) | (__float_as_uint(l1) & 0xffff0000u);
      }
      a[mi][0] = hh.v; a[mi][1] = mm.v; a[mi][2] = ll.v;
    }

    #pragma unroll
    for (int mat = 0; mat < NW; ++mat) {
      #pragma unroll
      for (int ni = 0; ni < 2; ++ni) {
        int nrow = (wcol >> 4) + ni;
        int rowp = nrow * 16 + c16;
        int off = ((mat * 2) * 64 + rowp) * WROW + kg * 8;
        bf16x8 bh = *(const bf16x8*)&Wlds[off];
        bf16x8 bm = *(const bf16x8*)&Wlds[off + 64 * WROW];
        bf16x8 bl = *(const bf16x8*)&Wt[(size_t)mat * 49152 + 32768 +
                                        (n0 + rowp) * 128 + ks * 32 + kg * 8];
        #pragma unroll
        for (int mi = 0; mi < 2; ++mi) {
          acc[mat][mi][ni] = __builtin_amdgcn_mfma_f32_16x16x32_bf16(a[mi][0], bh, acc[mat][mi][ni], 0, 0, 0);
          acc[mat][mi][ni] = __builtin_amdgcn_mfma_f32_16x16x32_bf16(a[mi][0], bm, acc[mat][mi][ni], 0, 0, 0);
          acc[mat][mi][ni] = __builtin_amdgcn_mfma_f32_16x16x32_bf16(a[mi][1], bh, acc[mat][mi][ni], 0, 0, 0);
          acc[mat][mi][ni] = __builtin_amdgcn_mfma_f32_16x16x32_bf16(a[mi][0], bl, acc[mat][mi][ni], 0, 0, 0);
          acc[mat][mi][ni] = __builtin_amdgcn_mfma_f32_16x16x32_bf16(a[mi][2], bh, acc[mat][mi][ni], 0, 0, 0);
          acc[mat][mi][ni] = __builtin_amdgcn_mfma_f32_16x16x32_bf16(a[mi][1], bm, acc[mat][mi][ni], 0, 0, 0);
        }
      }
    }
  }

  // epilogue
  float s1a[2][4], s2a[2][4];
  if (DOT) {
    #pragma unroll
    for (int mi = 0; mi < 2; ++mi)
      #pragma unroll
      for (int r = 0; r < 4; ++r) { s1a[mi][r] = 0.f; s2a[mi][r] = 0.f; }
  }
  float rdo[2][2];
  #pragma unroll
  for (int mi = 0; mi < 2; ++mi)
    #pragma unroll
    for (int ni = 0; ni < 2; ++ni) {
      int colg = n0 + wcol + ni * 16 + c16;
      float w1c = 0.f, w2c = 0.f;
      if (DOT) { w1c = dw1[colg]; w2c = dw2[colg]; }
      if (RDOUT) rdo[mi][ni] = 0.f;
      #pragma unroll
      for (int r = 0; r < 4; ++r) {
        size_t o = (row0 + mi * 16 + kg * 4 + r) * 128 + colg;
        if (DUAL) {
          out[o]  = acc[0][mi][ni][r] + bias[colg];
          out2[o] = acc[NW - 1][mi][ni][r] + bias2[colg];
        } else if (NW == 3) {
          float g = fmaxf(acc[0][mi][ni][r] + bias[colg], 0.f)
                  + fmaxf(acc[1][mi][ni][r] + bias[128 + colg], 0.f)
                  + fmaxf(acc[2][mi][ni][r] + bias[256 + colg], 0.f);
          out[o] = g;
          if (DOT) { s1a[mi][r] += g * w1c; s2a[mi][r] += g * w2c; }
        } else {
          float g = acc[0][mi][ni][r] + bias[colg];
          if (RELU) g = fmaxf(g, 0.f);
          if (RES) g += res[o];
          if (RDOUT) {
            int slot = (int)((row0 + mi * 16 + kg * 4 + r) & 127);
            rdo[mi][ni] += ro_w[slot] * g;
          } else {
            out[o] = g;
          }
        }
      }
      if (RDOUT) {
        int b = (int)(row0 >> 7);
        atomicAdd(&xg[b * 128 + colg], rdo[mi][ni]);
      }
    }
  if (DOT) {
    #pragma unroll
    for (int mi = 0; mi < 2; ++mi)
      #pragma unroll
      for (int r = 0; r < 4; ++r) {
        float v1 = s1a[mi][r], v2 = s2a[mi][r];
        v1 += __shfl_xor(v1, 1);  v2 += __shfl_xor(v2, 1);
        v1 += __shfl_xor(v1, 2);  v2 += __shfl_xor(v2, 2);
        v1 += __shfl_xor(v1, 4);  v2 += __shfl_xor(v2, 4);
        v1 += __shfl_xor(v1, 8);  v2 += __shfl_xor(v2, 8);
        if (c16 == 0) {
          size_t row = row0 + mi * 16 + kg * 4 + r;
          atomicAdd(&t1g[row], v1);
          atomicAdd(&t2g[row], v2);
        }
      }
  }
}

// ======================= edge aggregation (f32 out) + optional fused score =======================
template<bool SCORE>
__global__ __launch_bounds__(256) void agg4_kernel(
    const float* __restrict__ H, const int* __restrict__ rp, const int* __restrict__ col,
    const float* __restrict__ wgt, const float* __restrict__ dinv,
    float* __restrict__ out,
    const float* __restrict__ t1s, const float* __restrict__ t2s,
    const float* __restrict__ b1p, const float* __restrict__ b2p,
    float* __restrict__ scoreOut) {
  int g = blockIdx.x * 256 + threadIdx.x;
  int node = g >> 5;
  int l = g & 31;
  const float4* H4 = (const float4*)H;
  float dv = dinv[node];
  float4 acc = H4[(size_t)node * 32 + l];
  float sn = dv * dv;
  acc.x *= sn; acc.y *= sn; acc.z *= sn; acc.w *= sn;
  float s2 = 0.f;
  int beg = rp[node], end = rp[node + 1];
  for (int j = beg; j < end; ++j) {
    float w = wgt[j];
    int c = col[j];
    float4 hv = H4[(size_t)c * 32 + l];
    acc.x += w * hv.x; acc.y += w * hv.y; acc.z += w * hv.z; acc.w += w * hv.w;
    if (SCORE) { if (l == 0) s2 += w * t2s[c]; }
  }
  ((float4*)out)[(size_t)node * 32 + l] = acc;
  if (SCORE && l == 0) {
    float a2 = sn * t2s[node] + b2p[0] + s2;
    scoreOut[node] = 0.5f * (t1s[node] + b1p[0]) + 0.5f * a2;
  }
}

// ======================= GLA score (standalone, layer 2) =======================
__global__ void score_kernel(const float* __restrict__ t1, const float* __restrict__ t2,
                             const int* __restrict__ rp, const int* __restrict__ col,
                             const float* __restrict__ wgt, const float* __restrict__ dinv,
                             const float* __restrict__ b1p, const float* __restrict__ b2p,
                             float* __restrict__ out) {
  int i = blockIdx.x * 256 + threadIdx.x;
  if (i >= N_NODES) return;
  float dv = dinv[i];
  float a2 = dv * dv * t2[i] + b2p[0];
  int beg = rp[i], end = rp[i + 1];
  for (int j = beg; j < end; ++j) a2 += wgt[j] * t2[col[j]];
  out[i] = 0.5f * (t1[i] + b1p[0]) + 0.5f * a2;
}

// ======================= layer-weight softmax + combine + fused pool dot =======================
__global__ void xf_kernel(const float* __restrict__ x1, const float* __restrict__ x2,
                          const float* __restrict__ x3, const float* __restrict__ sc,
                          const float* __restrict__ w1, const float* __restrict__ w2,
                          float* __restrict__ xf, float* __restrict__ t1, float* __restrict__ t2) {
  size_t idx = (size_t)blockIdx.x * 256 + threadIdx.x;
  int i = (int)(idx >> 5);
  float s0 = sc[i], s1 = sc[N_NODES + i], s2 = sc[2 * N_NODES + i];
  float mx = fmaxf(s0, fmaxf(s1, s2));
  float e0 = __expf(s0 - mx), e1 = __expf(s1 - mx), e2 = __expf(s2 - mx);
  float inv = 1.f / (e0 + e1 + e2);
  e0 *= inv; e1 *= inv; e2 *= inv;
  float4 a = ((const float4*)x1)[idx];
  float4 b = ((const float4*)x2)[idx];
  float4 c = ((const float4*)x3)[idx];
  float4 o;
  o.x = e0 * a.x + e1 * b.x + e2 * c.x;
  o.y = e0 * a.y + e1 * b.y + e2 * c.y;
  o.z = e0 * a.z + e1 * b.z + e2 * c.z;
  o.w = e0 * a.w + e1 * b.w + e2 * c.w;
  ((float4*)xf)[idx] = o;

  int l = (int)(idx & 31);
  float4 w1v = ((const float4*)w1)[l];
  float4 w2v = ((const float4*)w2)[l];
  float d1 = o.x * w1v.x + o.y * w1v.y + o.z * w1v.z + o.w * w1v.w;
  float d2 = o.x * w2v.x + o.y * w2v.y + o.z * w2v.z + o.w * w2v.w;
  #pragma unroll
  for (int off = 1; off <= 16; off <<= 1) {
    d1 += __shfl_xor(d1, off);
    d2 += __shfl_xor(d2, off);
  }
  if (l == 0) { t1[i] = d1; t2[i] = d2; }
}

// ======================= top-k (stable descending) =======================
__global__ __launch_bounds__(512) void topk_kernel(const float* __restrict__ score,
                                                   int* __restrict__ idxO, float* __restrict__ valO) {
  int b = blockIdx.x;
  int t = threadIdx.x;
  __shared__ float s[512];
  float v = score[b * NPG + t];
  s[t] = v;
  __syncthreads();
  int rank = 0;
  for (int j = 0; j < 512; ++j) {
    float u = s[j];
    rank += (u > v) || (u == v && j < t);
  }
  if (rank < RATIO_K) { idxO[b * RATIO_K + rank] = t; valO[b * RATIO_K + rank] = v; }
}

// ======================= MFMA flash attention =======================
__global__ __launch_bounds__(256) void attn_mfma_kernel(
    const float* __restrict__ Q, const float* __restrict__ K,
    const float* __restrict__ V, float* __restrict__ O) {
  int bb = blockIdx.x >> 2, h = blockIdx.x & 3;
  int tid = threadIdx.x;
  int wave = tid >> 6, lane = tid & 63;
  int c16 = lane & 15, kg = lane >> 4;
  int qbase = wave * 32;
  const float cscale = 0.088388347648318447f;

  __shared__ float Vs[64][34];
  __shared__ unsigned char PwB[4][32 * 144];

  bf16x8 Qh[2], Ql[2];
  #pragma unroll
  for (int qt = 0; qt < 2; ++qt) {
    const float* qp = Q + ((size_t)bb * 128 + qbase + qt * 16 + c16) * 128 + h * 32 + kg * 8;
    float4 f0 = *(const float4*)qp;
    float4 f1 = *(const float4*)(qp + 4);
    float f[8] = {f0.x, f0.y, f0.z, f0.w, f1.x, f1.y, f1.z, f1.w};
    U8 hh, ll;
    #pragma unroll
    for (int j = 0; j < 8; ++j) { hh.u[j] = f2b(f[j]); ll.u[j] = f2b(f[j] - b2f(hh.u[j])); }
    Qh[qt] = hh.v; Ql[qt] = ll.v;
  }

  float m2[2] = {-3.0e38f, -3.0e38f};
  float l2[2] = {0.f, 0.f};
  f32x4 od[2][2];
  #pragma unroll
  for (int dt = 0; dt < 2; ++dt)
    #pragma unroll
    for (int qt = 0; qt < 2; ++qt) od[dt][qt] = (f32x4){0.f, 0.f, 0.f, 0.f};

  for (int kc = 0; kc < NPG; kc += 64) {
    if (kc) __syncthreads();
    {
      int j = tid >> 2, grp = tid & 3;
      const float* vp = V + ((size_t)bb * NPG + kc + j) * 128 + h * 32 + grp * 8;
      float4 v0 = *(const float4*)vp;
      float4 v1 = *(const float4*)(vp + 4);
      float* d = &Vs[j][grp * 8];
      *(float2*)&d[0] = make_float2(v0.x, v0.y);
      *(float2*)&d[2] = make_float2(v0.z, v0.w);
      *(float2*)&d[4] = make_float2(v1.x, v1.y);
      *(float2*)&d[6] = make_float2(v1.z, v1.w);
    }
    __syncthreads();

    f32x4 sac[2][4];
    #pragma unroll
    for (int qt = 0; qt < 2; ++qt)
      #pragma unroll
      for (int kt = 0; kt < 4; ++kt) sac[qt][kt] = (f32x4){0.f, 0.f, 0.f, 0.f};

    #pragma unroll
    for (int kt = 0; kt < 4; ++kt) {
      const float* kp = K + ((size_t)bb * NPG + kc + kt * 16 + c16) * 128 + h * 32 + kg * 8;
      float4 f0 = *(const float4*)kp;
      float4 f1 = *(const float4*)(kp + 4);
      float f[8] = {f0.x, f0.y, f0.z, f0.w, f1.x, f1.y, f1.z, f1.w};
      U8 hh, ll;
      #pragma unroll
      for (int j = 0; j < 8; ++j) { hh.u[j] = f2b(f[j]); ll.u[j] = f2b(f[j] - b2f(hh.u[j])); }
      #pragma unroll
      for (int qt = 0; qt < 2; ++qt) {
        sac[qt][kt] = __builtin_amdgcn_mfma_f32_16x16x32_bf16(hh.v, Qh[qt], sac[qt][kt], 0, 0, 0);
        sac[qt][kt] = __builtin_amdgcn_mfma_f32_16x16x32_bf16(hh.v, Ql[qt], sac[qt][kt], 0, 0, 0);
        sac[qt][kt] = __builtin_amdgcn_mfma_f32_16x16x32_bf16(ll.v, Qh[qt], sac[qt][kt], 0, 0, 0);
      }
    }

    float pj[2][16];
    float scl2[2];
    #pragma unroll
    for (int qt = 0; qt < 2; ++qt) {
      float mc = -3.0e38f;
      #pragma unroll
      for (int kt = 0; kt < 4; ++kt)
        #pragma unroll
        for (int r = 0; r < 4; ++r) {
          float v = sac[qt][kt][r] * cscale;
          pj[qt][kt * 4 + r] = v;
          mc = fmaxf(mc, v);
        }
      mc = fmaxf(mc, __shfl_xor(mc, 16));
      mc = fmaxf(mc, __shfl_xor(mc, 32));
      float mnew = fmaxf(m2[qt], mc);
      float scl = __expf(m2[qt] - mnew);
      float ls = 0.f;
      #pragma unroll
      for (int i = 0; i < 16; ++i) {
        float e = __expf(pj[qt][i] - mnew);
        pj[qt][i] = e;
        ls += e;
      }
      ls += __shfl_xor(ls, 16);
      ls += __shfl_xor(ls, 32);
      l2[qt] = l2[qt] * scl + ls;
      m2[qt] = mnew;
      scl2[qt] = scl;
    }
    #pragma unroll
    for (int dt = 0; dt < 2; ++dt)
      #pragma unroll
      for (int qt = 0; qt < 2; ++qt) {
        #pragma unroll
        for (int r = 0; r < 4; ++r) od[dt][qt][r] *= scl2[qt];
      }

    #pragma unroll
    for (int qt = 0; qt < 2; ++qt) {
      int q32 = qt * 16 + c16;
      unsigned char* pb = &PwB[wave][q32 * 144];
      unsigned sw = (unsigned)((q32 & 7) << 4);
      #pragma unroll
      for (int kt = 0; kt < 4; ++kt)
        #pragma unroll
        for (int rp = 0; rp < 2; ++rp) {
          unsigned pk = (unsigned)f2b(pj[qt][kt * 4 + 2 * rp]) |
                        ((unsigned)f2b(pj[qt][kt * 4 + 2 * rp + 1]) << 16);
          *(unsigned*)&pb[((unsigned)(kt * 32 + kg * 8 + 4 * rp)) ^ sw] = pk;
        }
    }

    #pragma unroll
    for (int kw = 0; kw < 2; ++kw) {
      bf16x8 Pb[2];
      #pragma unroll
      for (int qt = 0; qt < 2; ++qt) {
        int q32 = qt * 16 + c16;
        Pb[qt] = *(const bf16x8*)&PwB[wave][q32 * 144 +
                   (((unsigned)(kw * 64 + kg * 16)) ^ ((unsigned)((q32 & 7) << 4)))];
      }
      #pragma unroll
      for (int dt = 0; dt < 2; ++dt) {
        U8 vh, vl;
        #pragma unroll
        for (int j = 0; j < 8; ++j) {
          float v = Vs[kw * 32 + kg * 8 + j][dt * 16 + c16];
          vh.u[j] = f2b(v);
          vl.u[j] = f2b(v - b2f(vh.u[j]));
        }
        #pragma unroll
        for (int qt = 0; qt < 2; ++qt) {
          od[dt][qt] = __builtin_amdgcn_mfma_f32_16x16x32_bf16(vh.v, Pb[qt], od[dt][qt], 0, 0, 0);
          od[dt][qt] = __builtin_amdgcn_mfma_f32_16x16x32_bf16(vl.v, Pb[qt], od[dt][qt], 0, 0, 0);
        }
      }
    }
  }

  #pragma unroll
  for (int qt = 0; qt < 2; ++qt) {
    float inv = 1.f / l2[qt];
    size_t row = (size_t)bb * 128 + qbase + qt * 16 + c16;
    #pragma unroll
    for (int dt = 0; dt < 2; ++dt)
      #pragma unroll
      for (int r = 0; r < 4; ++r) {
        int colg = h * 32 + dt * 16 + kg * 4 + r;
        O[row * 128 + colg] = Q[row * 128 + colg] + od[dt][qt][r] * inv;
      }
  }
}

// ======================= xg init (= ro_b) =======================
__global__ void xg_init_kernel(float* __restrict__ xg, const float* __restrict__ ro_b) {
  int i = blockIdx.x * 256 + threadIdx.x;
  if (i < BGRAPH * DD) xg[i] = ro_b[0];
}

// ======================= fused classifier + log-softmax head (+ xg passthrough) =======================
__global__ __launch_bounds__(128) void clshead_kernel(
    const float* __restrict__ xg, const float* __restrict__ c1w, const float* __restrict__ c1b,
    const float* __restrict__ c2w, const float* __restrict__ c2b, float* __restrict__ out) {
  int b = blockIdx.x, t = threadIdx.x;
  __shared__ float xr[128];
  __shared__ float hc[128];
  __shared__ float z[10];
  __shared__ float lse_s;
  float xv = xg[b * 128 + t];
  xr[t] = xv;
  out[BGRAPH * 10 + b * 128 + t] = xv;   // xg output (tail of d_out)
  __syncthreads();
  float s = c1b[t];
  for (int k = 0; k < 128; ++k) s += xr[k] * c1w[k * 128 + t];
  hc[t] = fmaxf(s, 0.f);
  __syncthreads();
  if (t < 10) {
    float s2 = c2b[t];
    for (int k = 0; k < 128; ++k) s2 += hc[k] * c2w[k * 10 + t];
    z[t] = s2;
  }
  __syncthreads();
  if (t == 0) {
    float mx = z[0];
    for (int c = 1; c < 10; ++c) mx = fmaxf(mx, z[c]);
    float sum = 0.f;
    for (int c = 0; c < 10; ++c) sum += expf(z[c] - mx);
    lse_s = mx + logf(sum);
  }
  __syncthreads();
  if (t < 10) out[b * 10 + t] = z[t] - lse_s;
}

// ======================= launcher =======================
extern "C" void kernel_launch(void* const* d_in, const int* in_sizes, int n_in,
                              void* d_out, int out_size, void* d_ws, size_t ws_size,
                              hipStream_t stream) {
  const float* x       = (const float*)d_in[0];
  const int*   edge    = (const int*)d_in[1];
  const float* enc_w   = (const float*)d_in[2];
  const float* enc_b   = (const float*)d_in[3];
  const float* gconv_w = (const float*)d_in[4];
  const float* gconv_b = (const float*)d_in[5];
  const float* wg1_w   = (const float*)d_in[6];
  const float* wg1_b   = (const float*)d_in[7];
  const float* wg2_w   = (const float*)d_in[8];
  const float* wg2_b   = (const float*)d_in[9];
  const float* pg1_w   = (const float*)d_in[10];
  const float* pg1_b   = (const float*)d_in[11];
  const float* pg2_w   = (const float*)d_in[12];
  const float* pg2_b   = (const float*)d_in[13];
  const float* q_w     = (const float*)d_in[14];
  const float* q_b     = (const float*)d_in[15];
  const float* k_w     = (const float*)d_in[16];
  const float* k_b     = (const float*)d_in[17];
  const float* v_w     = (const float*)d_in[18];
  const float* v_b     = (const float*)d_in[19];
  const float* o_w     = (const float*)d_in[20];
  const float* o_b     = (const float*)d_in[21];
  const float* ro_w    = (const float*)d_in[22];
  const float* ro_b    = (const float*)d_in[23];
  const float* c1_w    = (const float*)d_in[24];
  const float* c1_b    = (const float*)d_in[25];
  const float* c2_w    = (const float*)d_in[26];
  const float* c2_b    = (const float*)d_in[27];

  float* outp = (float*)d_out;

  const size_t S = (size_t)N_NODES * DD;
  float* ws    = (float*)d_ws;
  float* slot0 = ws;
  float* slot1 = ws + S;
  float* slot2 = ws + 2 * S;
  float* slot3 = ws + 3 * S;
  float* smallf = ws + 4 * S;
  int*   cnt  = (int*)smallf;
  int*   fill = cnt + N_NODES;
  int*   rp   = fill + N_NODES;
  int*   col  = rp + N_NODES + 8;
  float* wgt  = (float*)(col + NE);
  float* dinv = wgt + NE;
  float* sc   = dinv + N_NODES;
  float* tb   = sc + 3 * N_NODES;
  float* score = tb + 8 * N_NODES;
  int*   tidx = (int*)(score + N_NODES);
  float* tval = (float*)(tidx + BGRAPH * RATIO_K);
  float* xg   = tval + BGRAPH * RATIO_K;
  unsigned short* wsW = (unsigned short*)(xg + BGRAPH * DD);
  float* aggbuf = (float*)(wsW + 14 * 49152);

  float* t1_0 = tb;
  float* t2_0 = tb + N_NODES;
  float* t1_1 = tb + 2 * N_NODES;
  float* t2_1 = tb + 3 * N_NODES;
  float* t1_2 = tb + 4 * N_NODES;
  float* t2_2 = tb + 5 * N_NODES;
  float* t1_p = tb + 6 * N_NODES;
  float* t2_p = tb + 7 * N_NODES;

  const size_t SP = (size_t)BGRAPH * RATIO_K * DD;
  float* Qm = slot3 + SP;
  float* Om = slot3 + 2 * SP;

  // ---- graph preprocessing ----
  hipMemsetAsync(cnt, 0, N_NODES * sizeof(int), stream);
  hipMemsetAsync(fill, 0, N_NODES * sizeof(int), stream);
  hipMemsetAsync(tb, 0, 8 * N_NODES * sizeof(float), stream);
  count_kernel<<<NE / 256, 256, 0, stream>>>(edge + NE, cnt);
  dinv_kernel<<<N_NODES / 256, 256, 0, stream>>>(cnt, dinv);
  scan_kernel2<<<BGRAPH, 512, 0, stream>>>(cnt, rp);
  scatter_kernel<<<NE / 256, 256, 0, stream>>>(edge, rp, fill, dinv, col, wgt);

  // ---- weight prep ----
  WPtrs wp;
  wp.p[0] = enc_w;
  for (int i = 0; i < 9; ++i) wp.p[1 + i] = gconv_w + (size_t)i * DD * DD;
  wp.p[10] = k_w; wp.p[11] = v_w; wp.p[12] = q_w; wp.p[13] = o_w;
  wprep_all<<<dim3(64, 14), 256, 0, stream>>>(wp, wsW);

  // ---- encoder ----
  mfma_gemm8<1, false, false, false, false, false, false><<<dim3(2, 1024), 256, 0, stream>>>(
      x, wsW, enc_b, nullptr, nullptr, slot0, nullptr,
      nullptr, nullptr, nullptr, nullptr, nullptr, nullptr, nullptr, nullptr);

  const int AGG_GRID = (N_NODES * 32) / 256;
  float* lin[4] = {slot0, slot1, slot2, slot3};
  float* t1s[3] = {t1_0, t1_1, t1_2};
  float* t2s[3] = {t2_0, t2_1, t2_2};

  // ---- layer 0 ----
  agg4_kernel<false><<<AGG_GRID, 256, 0, stream>>>(
      lin[0], rp, col, wgt, dinv, aggbuf, nullptr, nullptr, nullptr, nullptr, nullptr);
  mfma_gemm8<3, true, false, false, true, false, false><<<dim3(2, 1024), 256, 0, stream>>>(
      aggbuf, wsW + 1 * 49152UL, gconv_b, nullptr, nullptr, lin[1], nullptr,
      wg1_w, wg2_w, t1_0, t2_0, nullptr, nullptr, nullptr, nullptr);

  // ---- layers 1,2 with fused prev-layer score ----
  for (int l = 1; l < 3; ++l) {
    agg4_kernel<true><<<AGG_GRID, 256, 0, stream>>>(
        lin[l], rp, col, wgt, dinv, aggbuf,
        t1s[l - 1], t2s[l - 1], wg1_b, wg2_b, sc + (size_t)(l - 1) * N_NODES);
    mfma_gemm8<3, true, false, false, true, false, false><<<dim3(2, 1024), 256, 0, stream>>>(
        aggbuf, wsW + (size_t)(1 + l * 3) * 49152, gconv_b + (size_t)l * 3 * DD,
        nullptr, nullptr, lin[l + 1], nullptr,
        wg1_w, wg2_w, t1s[l], t2s[l], nullptr, nullptr, nullptr, nullptr);
  }

  // ---- layer-2 score ----
  score_kernel<<<N_NODES / 256, 256, 0, stream>>>(t1_2, t2_2, rp, col, wgt, dinv, wg1_b, wg2_b, sc + 2 * (size_t)N_NODES);

  // ---- xf (+ fused pooling dot) ----
  float* xf = slot0;
  xf_kernel<<<(N_NODES * 32) / 256, 256, 0, stream>>>(slot1, slot2, slot3, sc, pg1_w, pg2_w, xf, t1_p, t2_p);

  // ---- K/V aggregation with fused pooling score ----
  agg4_kernel<true><<<AGG_GRID, 256, 0, stream>>>(
      xf, rp, col, wgt, dinv, aggbuf, t1_p, t2_p, pg1_b, pg2_b, score);

  // ---- top-k ----
  topk_kernel<<<BGRAPH, 512, 0, stream>>>(score, tidx, tval);

  // ---- Q GEMM with fused pooled-gather ----
  mfma_gemm8<1, false, false, false, false, true, false><<<dim3(2, 256), 256, 0, stream>>>(
      xf, wsW + 12 * 49152UL, q_b, nullptr, nullptr, Qm, nullptr,
      nullptr, nullptr, nullptr, nullptr, tidx, tval, nullptr, nullptr);

  // ---- fused K+V GEMM ----
  mfma_gemm8<2, false, false, true, false, false, false><<<dim3(2, 1024), 256, 0, stream>>>(
      aggbuf, wsW + 10 * 49152UL, k_b, v_b, nullptr, slot1, slot2,
      nullptr, nullptr, nullptr, nullptr, nullptr, nullptr, nullptr, nullptr);

  // ---- attention ----
  attn_mfma_kernel<<<BGRAPH * NHEAD, 256, 0, stream>>>(Qm, slot1, slot2, Om);

  // ---- xg init; O-GEMM with fused conv1d readout ----
  xg_init_kernel<<<(BGRAPH * DD) / 256, 256, 0, stream>>>(xg, ro_b);
  mfma_gemm8<1, true, true, false, false, false, true><<<dim3(2, 256), 256, 0, stream>>>(
      Om, wsW + 13 * 49152UL, o_b, nullptr, Om, nullptr, nullptr,
      nullptr, nullptr, nullptr, nullptr, nullptr, nullptr, ro_w, xg);

  // ---- fused classifier + head (also writes xg to d_out tail) ----
  clshead_kernel<<<BGRAPH, 128, 0, stream>>>(xg, c1_w, c1_b, c2_w, c2_b, outp);
}

// Round 19
// 613.983 us; speedup vs baseline: 1.0216x; 1.0216x over previous
//
#include <hip/hip_runtime.h>
#include <math.h>

#define N_NODES 65536
#define NE      524288
#define DD      128
#define BGRAPH  128
#define NPG     512
#define RATIO_K 128
#define NHEAD   4
#define DHEAD   32

typedef short bf16x8 __attribute__((ext_vector_type(8)));
typedef float f32x4 __attribute__((ext_vector_type(4)));

union U8 { unsigned short u[8]; bf16x8 v; };
union U4x { unsigned q[4]; bf16x8 v; };

__device__ __forceinline__ unsigned short f2b(float f) {
  unsigned u = __float_as_uint(f);
  unsigned r = u + 0x7fffu + ((u >> 16) & 1u);   // RTNE
  return (unsigned short)(r >> 16);
}
__device__ __forceinline__ float b2f(unsigned short h) {
  return __uint_as_float(((unsigned)h) << 16);
}
__device__ __forceinline__ void split3t(float v, unsigned short& h, unsigned short& m, unsigned short& l) {
  unsigned u = __float_as_uint(v);
  h = (unsigned short)(u >> 16);
  float vm = v - __uint_as_float(u & 0xffff0000u);
  unsigned um = __float_as_uint(vm);
  m = (unsigned short)(um >> 16);
  float vl = vm - __uint_as_float(um & 0xffff0000u);
  l = (unsigned short)(__float_as_uint(vl) >> 16);
}

// ======================= graph preprocessing =======================

__global__ void count_kernel(const int* __restrict__ dst, int* __restrict__ cnt) {
  int e = blockIdx.x * 256 + threadIdx.x;
  if (e < NE) atomicAdd(&cnt[dst[e]], 1);
}

__global__ void dinv_kernel(const int* __restrict__ cnt, float* __restrict__ dinv) {
  int i = blockIdx.x * 256 + threadIdx.x;
  if (i < N_NODES) dinv[i] = rsqrtf((float)cnt[i] + 1.0f);
}

__global__ __launch_bounds__(512) void scan_kernel2(const int* __restrict__ cnt, int* __restrict__ rp) {
  __shared__ int part[512];
  int g = blockIdx.x, t = threadIdx.x;
  int v = cnt[g * 512 + t];
  part[t] = v;
  __syncthreads();
  for (int off = 1; off < 512; off <<= 1) {
    int u = (t >= off) ? part[t - off] : 0;
    __syncthreads();
    part[t] += u;
    __syncthreads();
  }
  rp[g * 512 + t] = g * 4096 + part[t] - v;   // exclusive
  if (g == BGRAPH - 1 && t == 511) rp[N_NODES] = NE;
}

__global__ void scatter_kernel(const int* __restrict__ edge, const int* __restrict__ rp,
                               int* __restrict__ fill, const float* __restrict__ dinv,
                               int* __restrict__ col, float* __restrict__ wgt) {
  int e = blockIdx.x * 256 + threadIdx.x;
  if (e >= NE) return;
  int s = edge[e];
  int d = edge[NE + e];
  int p = rp[d] + atomicAdd(&fill[d], 1);
  col[p] = s;
  wgt[p] = dinv[s] * dinv[d];
}

// ======================= weight prep (all 14 mats in one launch) =======================
struct WPtrs { const float* p[14]; };

__global__ void wprep_all(WPtrs wp, unsigned short* __restrict__ dstBase) {
  int mat = blockIdx.y;
  int idx = blockIdx.x * 256 + threadIdx.x;
  const float* __restrict__ W = wp.p[mat];
  unsigned short* __restrict__ dst = dstBase + (size_t)mat * 49152;
  int k = idx >> 7, n = idx & 127;
  float v = W[k * 128 + n];
  unsigned short h, m, l;
  split3t(v, h, m, l);
  dst[n * 128 + k] = h;
  dst[16384 + n * 128 + k] = m;
  dst[32768 + n * 128 + k] = l;
}

// ======================= MFMA GEMM: 3-plane LDS staging, WROW=36 (best-known config) =======================
#define WROW 36

template<int NW, bool RELU, bool RES, bool DUAL, bool DOT, bool GATHER, bool RDOUT>
__global__ __launch_bounds__(256, 2) void mfma_gemm8(
    const float* __restrict__ A,
    const unsigned short* __restrict__ Wt,
    const float* __restrict__ bias, const float* __restrict__ bias2,
    const float* __restrict__ res,
    float* __restrict__ out, float* __restrict__ out2,
    const float* __restrict__ dw1, const float* __restrict__ dw2,
    float* __restrict__ t1g, float* __restrict__ t2g,
    const int* __restrict__ tidxp, const float* __restrict__ tvalp,
    const float* __restrict__ ro_w, float* __restrict__ xg) {
  __shared__ unsigned short Wlds[NW * 3 * 64 * WROW];
  int tid = threadIdx.x;
  int wave = tid >> 6, lane = tid & 63;
  int c16 = lane & 15, kg = lane >> 4;
  int wrow = (wave >> 1) * 32;
  int wcol = (wave & 1) * 32;
  size_t row0 = (size_t)blockIdx.y * 64 + wrow;
  int n0 = blockIdx.x * 64;

  const float* arow[2];
  float ascale[2];
  #pragma unroll
  for (int mi = 0; mi < 2; ++mi) {
    size_t gr = row0 + mi * 16 + c16;
    if (GATHER) {
      int b = (int)(gr >> 7);
      int node = tidxp[gr];
      arow[mi] = A + ((size_t)b * NPG + node) * DD;
      ascale[mi] = tanhf(tvalp[gr]);
    } else {
      arow[mi] = A + gr * DD;
      ascale[mi] = 1.f;
    }
  }

  f32x4 acc[NW][2][2];
  #pragma unroll
  for (int m = 0; m < NW; ++m)
    #pragma unroll
    for (int mi = 0; mi < 2; ++mi)
      #pragma unroll
      for (int ni = 0; ni < 2; ++ni) acc[m][mi][ni] = (f32x4){0.f, 0.f, 0.f, 0.f};

  for (int ks = 0; ks < 4; ++ks) {
    if (ks) __syncthreads();
    #pragma unroll
    for (int i = 0; i < NW * 3; ++i) {
      int c = tid + i * 256;
      int u4 = c & 3;
      int n = (c >> 2) & 63;
      int mp = c >> 8;
      *(uint4*)&Wlds[(mp * 64 + n) * WROW + u4 * 8] =
          *(const uint4*)&Wt[(size_t)mp * 16384 + (n0 + n) * 128 + ks * 32 + u4 * 8];
    }
    __syncthreads();

    bf16x8 a[2][3];
    #pragma unroll
    for (int mi = 0; mi < 2; ++mi) {
      const float* ap = arow[mi] + ks * 32 + kg * 8;
      float4 f0 = *(const float4*)ap;
      float4 f1 = *(const float4*)(ap + 4);
      float f[8] = {f0.x, f0.y, f0.z, f0.w, f1.x, f1.y, f1.z, f1.w};
      if (GATHER) {
        #pragma unroll
        for (int j = 0; j < 8; ++j) f[j] *= ascale[mi];
      }
      U4x hh, mm, ll;
      #pragma unroll
      for (int p = 0; p < 4; ++p) {
        float v0 = f[2 * p], v1 = f[2 * p + 1];
        unsigned u0 = __float_as_uint(v0), u1 = __float_as_uint(v1);
        unsigned u1m = u1 & 0xffff0000u;
        hh.q[p] = (u0 >> 16) | u1m;
        float m0 = v0 - __uint_as_float(u0 & 0xffff0000u);
        float m1 = v1 - __uint_as_float(u1m);
        unsigned w0 = __float_as_uint(m0), w1 = __float_as_uint(m1);
        unsigned w1m = w1 & 0xffff0000u;
        mm.q[p] = (w0 >> 16) | w1m;
        float l0 = m0 - __uint_as_float(w0 & 0xffff0000u);
        float l1 = m1 - __uint_as_float(w1m);
        ll.q[p] = (__float_as_uint(l0) >> 16) | (__float_as_uint(l1) & 0xffff0000u);
      }
      a[mi][0] = hh.v; a[mi][1] = mm.v; a[mi][2] = ll.v;
    }

    #pragma unroll
    for (int mat = 0; mat < NW; ++mat) {
      #pragma unroll
      for (int ni = 0; ni < 2; ++ni) {
        int nrow = (wcol >> 4) + ni;
        int off = ((mat * 3) * 64 + nrow * 16 + c16) * WROW + kg * 8;
        bf16x8 bh = *(const bf16x8*)&Wlds[off];
        bf16x8 bm = *(const bf16x8*)&Wlds[off + 64 * WROW];
        bf16x8 bl = *(const bf16x8*)&Wlds[off + 128 * WROW];
        #pragma unroll
        for (int mi = 0; mi < 2; ++mi) {
          acc[mat][mi][ni] = __builtin_amdgcn_mfma_f32_16x16x32_bf16(a[mi][0], bh, acc[mat][mi][ni], 0, 0, 0);
          acc[mat][mi][ni] = __builtin_amdgcn_mfma_f32_16x16x32_bf16(a[mi][0], bm, acc[mat][mi][ni], 0, 0, 0);
          acc[mat][mi][ni] = __builtin_amdgcn_mfma_f32_16x16x32_bf16(a[mi][1], bh, acc[mat][mi][ni], 0, 0, 0);
          acc[mat][mi][ni] = __builtin_amdgcn_mfma_f32_16x16x32_bf16(a[mi][0], bl, acc[mat][mi][ni], 0, 0, 0);
          acc[mat][mi][ni] = __builtin_amdgcn_mfma_f32_16x16x32_bf16(a[mi][2], bh, acc[mat][mi][ni], 0, 0, 0);
          acc[mat][mi][ni] = __builtin_amdgcn_mfma_f32_16x16x32_bf16(a[mi][1], bm, acc[mat][mi][ni], 0, 0, 0);
        }
      }
    }
  }

  // epilogue
  float s1a[2][4], s2a[2][4];
  if (DOT) {
    #pragma unroll
    for (int mi = 0; mi < 2; ++mi)
      #pragma unroll
      for (int r = 0; r < 4; ++r) { s1a[mi][r] = 0.f; s2a[mi][r] = 0.f; }
  }
  float rdo[2][2];
  #pragma unroll
  for (int mi = 0; mi < 2; ++mi)
    #pragma unroll
    for (int ni = 0; ni < 2; ++ni) {
      int colg = n0 + wcol + ni * 16 + c16;
      float w1c = 0.f, w2c = 0.f;
      if (DOT) { w1c = dw1[colg]; w2c = dw2[colg]; }
      if (RDOUT) rdo[mi][ni] = 0.f;
      #pragma unroll
      for (int r = 0; r < 4; ++r) {
        size_t o = (row0 + mi * 16 + kg * 4 + r) * 128 + colg;
        if (DUAL) {
          out[o]  = acc[0][mi][ni][r] + bias[colg];
          out2[o] = acc[NW - 1][mi][ni][r] + bias2[colg];
        } else if (NW == 3) {
          float g = fmaxf(acc[0][mi][ni][r] + bias[colg], 0.f)
                  + fmaxf(acc[1][mi][ni][r] + bias[128 + colg], 0.f)
                  + fmaxf(acc[2][mi][ni][r] + bias[256 + colg], 0.f);
          out[o] = g;
          if (DOT) { s1a[mi][r] += g * w1c; s2a[mi][r] += g * w2c; }
        } else {
          float g = acc[0][mi][ni][r] + bias[colg];
          if (RELU) g = fmaxf(g, 0.f);
          if (RES) g += res[o];
          if (RDOUT) {
            int slot = (int)((row0 + mi * 16 + kg * 4 + r) & 127);
            rdo[mi][ni] += ro_w[slot] * g;
          } else {
            out[o] = g;
          }
        }
      }
      if (RDOUT) {
        int b = (int)(row0 >> 7);
        atomicAdd(&xg[b * 128 + colg], rdo[mi][ni]);
      }
    }
  if (DOT) {
    #pragma unroll
    for (int mi = 0; mi < 2; ++mi)
      #pragma unroll
      for (int r = 0; r < 4; ++r) {
        float v1 = s1a[mi][r], v2 = s2a[mi][r];
        v1 += __shfl_xor(v1, 1);  v2 += __shfl_xor(v2, 1);
        v1 += __shfl_xor(v1, 2);  v2 += __shfl_xor(v2, 2);
        v1 += __shfl_xor(v1, 4);  v2 += __shfl_xor(v2, 4);
        v1 += __shfl_xor(v1, 8);  v2 += __shfl_xor(v2, 8);
        if (c16 == 0) {
          size_t row = row0 + mi * 16 + kg * 4 + r;
          atomicAdd(&t1g[row], v1);
          atomicAdd(&t2g[row], v2);
        }
      }
  }
}

// ======================= edge aggregation (f32 out) + optional fused score =======================
template<bool SCORE>
__global__ __launch_bounds__(256) void agg4_kernel(
    const float* __restrict__ H, const int* __restrict__ rp, const int* __restrict__ col,
    const float* __restrict__ wgt, const float* __restrict__ dinv,
    float* __restrict__ out,
    const float* __restrict__ t1s, const float* __restrict__ t2s,
    const float* __restrict__ b1p, const float* __restrict__ b2p,
    float* __restrict__ scoreOut) {
  int g = blockIdx.x * 256 + threadIdx.x;
  int node = g >> 5;
  int l = g & 31;
  const float4* H4 = (const float4*)H;
  float dv = dinv[node];
  float4 acc = H4[(size_t)node * 32 + l];
  float sn = dv * dv;
  acc.x *= sn; acc.y *= sn; acc.z *= sn; acc.w *= sn;
  float s2 = 0.f;
  int beg = rp[node], end = rp[node + 1];
  for (int j = beg; j < end; ++j) {
    float w = wgt[j];
    int c = col[j];
    float4 hv = H4[(size_t)c * 32 + l];
    acc.x += w * hv.x; acc.y += w * hv.y; acc.z += w * hv.z; acc.w += w * hv.w;
    if (SCORE) { if (l == 0) s2 += w * t2s[c]; }
  }
  ((float4*)out)[(size_t)node * 32 + l] = acc;
  if (SCORE && l == 0) {
    float a2 = sn * t2s[node] + b2p[0] + s2;
    scoreOut[node] = 0.5f * (t1s[node] + b1p[0]) + 0.5f * a2;
  }
}

// ======================= GLA score (standalone, layer 2) =======================
__global__ void score_kernel(const float* __restrict__ t1, const float* __restrict__ t2,
                             const int* __restrict__ rp, const int* __restrict__ col,
                             const float* __restrict__ wgt, const float* __restrict__ dinv,
                             const float* __restrict__ b1p, const float* __restrict__ b2p,
                             float* __restrict__ out) {
  int i = blockIdx.x * 256 + threadIdx.x;
  if (i >= N_NODES) return;
  float dv = dinv[i];
  float a2 = dv * dv * t2[i] + b2p[0];
  int beg = rp[i], end = rp[i + 1];
  for (int j = beg; j < end; ++j) a2 += wgt[j] * t2[col[j]];
  out[i] = 0.5f * (t1[i] + b1p[0]) + 0.5f * a2;
}

// ======================= layer-weight softmax + combine + fused pool dot =======================
__global__ void xf_kernel(const float* __restrict__ x1, const float* __restrict__ x2,
                          const float* __restrict__ x3, const float* __restrict__ sc,
                          const float* __restrict__ w1, const float* __restrict__ w2,
                          float* __restrict__ xf, float* __restrict__ t1, float* __restrict__ t2) {
  size_t idx = (size_t)blockIdx.x * 256 + threadIdx.x;
  int i = (int)(idx >> 5);
  float s0 = sc[i], s1 = sc[N_NODES + i], s2 = sc[2 * N_NODES + i];
  float mx = fmaxf(s0, fmaxf(s1, s2));
  float e0 = __expf(s0 - mx), e1 = __expf(s1 - mx), e2 = __expf(s2 - mx);
  float inv = 1.f / (e0 + e1 + e2);
  e0 *= inv; e1 *= inv; e2 *= inv;
  float4 a = ((const float4*)x1)[idx];
  float4 b = ((const float4*)x2)[idx];
  float4 c = ((const float4*)x3)[idx];
  float4 o;
  o.x = e0 * a.x + e1 * b.x + e2 * c.x;
  o.y = e0 * a.y + e1 * b.y + e2 * c.y;
  o.z = e0 * a.z + e1 * b.z + e2 * c.z;
  o.w = e0 * a.w + e1 * b.w + e2 * c.w;
  ((float4*)xf)[idx] = o;

  int l = (int)(idx & 31);
  float4 w1v = ((const float4*)w1)[l];
  float4 w2v = ((const float4*)w2)[l];
  float d1 = o.x * w1v.x + o.y * w1v.y + o.z * w1v.z + o.w * w1v.w;
  float d2 = o.x * w2v.x + o.y * w2v.y + o.z * w2v.z + o.w * w2v.w;
  #pragma unroll
  for (int off = 1; off <= 16; off <<= 1) {
    d1 += __shfl_xor(d1, off);
    d2 += __shfl_xor(d2, off);
  }
  if (l == 0) { t1[i] = d1; t2[i] = d2; }
}

// ======================= top-k (stable descending) =======================
__global__ __launch_bounds__(512) void topk_kernel(const float* __restrict__ score,
                                                   int* __restrict__ idxO, float* __restrict__ valO) {
  int b = blockIdx.x;
  int t = threadIdx.x;
  __shared__ float s[512];
  float v = score[b * NPG + t];
  s[t] = v;
  __syncthreads();
  int rank = 0;
  for (int j = 0; j < 512; ++j) {
    float u = s[j];
    rank += (u > v) || (u == v && j < t);
  }
  if (rank < RATIO_K) { idxO[b * RATIO_K + rank] = t; valO[b * RATIO_K + rank] = v; }
}

// ======================= MFMA flash attention =======================
__global__ __launch_bounds__(256) void attn_mfma_kernel(
    const float* __restrict__ Q, const float* __restrict__ K,
    const float* __restrict__ V, float* __restrict__ O) {
  int bb = blockIdx.x >> 2, h = blockIdx.x & 3;
  int tid = threadIdx.x;
  int wave = tid >> 6, lane = tid & 63;
  int c16 = lane & 15, kg = lane >> 4;
  int qbase = wave * 32;
  const float cscale = 0.088388347648318447f;

  __shared__ float Vs[64][34];
  __shared__ unsigned char PwB[4][32 * 144];

  bf16x8 Qh[2], Ql[2];
  #pragma unroll
  for (int qt = 0; qt < 2; ++qt) {
    const float* qp = Q + ((size_t)bb * 128 + qbase + qt * 16 + c16) * 128 + h * 32 + kg * 8;
    float4 f0 = *(const float4*)qp;
    float4 f1 = *(const float4*)(qp + 4);
    float f[8] = {f0.x, f0.y, f0.z, f0.w, f1.x, f1.y, f1.z, f1.w};
    U8 hh, ll;
    #pragma unroll
    for (int j = 0; j < 8; ++j) { hh.u[j] = f2b(f[j]); ll.u[j] = f2b(f[j] - b2f(hh.u[j])); }
    Qh[qt] = hh.v; Ql[qt] = ll.v;
  }

  float m2[2] = {-3.0e38f, -3.0e38f};
  float l2[2] = {0.f, 0.f};
  f32x4 od[2][2];
  #pragma unroll
  for (int dt = 0; dt < 2; ++dt)
    #pragma unroll
    for (int qt = 0; qt < 2; ++qt) od[dt][qt] = (f32x4){0.f, 0.f, 0.f, 0.f};

  for (int kc = 0; kc < NPG; kc += 64) {
    if (kc) __syncthreads();
    {
      int j = tid >> 2, grp = tid & 3;
      const float* vp = V + ((size_t)bb * NPG + kc + j) * 128 + h * 32 + grp * 8;
      float4 v0 = *(const float4*)vp;
      float4 v1 = *(const float4*)(vp + 4);
      float* d = &Vs[j][grp * 8];
      *(float2*)&d[0] = make_float2(v0.x, v0.y);
      *(float2*)&d[2] = make_float2(v0.z, v0.w);
      *(float2*)&d[4] = make_float2(v1.x, v1.y);
      *(float2*)&d[6] = make_float2(v1.z, v1.w);
    }
    __syncthreads();

    f32x4 sac[2][4];
    #pragma unroll
    for (int qt = 0; qt < 2; ++qt)
      #pragma unroll
      for (int kt = 0; kt < 4; ++kt) sac[qt][kt] = (f32x4){0.f, 0.f, 0.f, 0.f};

    #pragma unroll
    for (int kt = 0; kt < 4; ++kt) {
      const float* kp = K + ((size_t)bb * NPG + kc + kt * 16 + c16) * 128 + h * 32 + kg * 8;
      float4 f0 = *(const float4*)kp;
      float4 f1 = *(const float4*)(kp + 4);
      float f[8] = {f0.x, f0.y, f0.z, f0.w, f1.x, f1.y, f1.z, f1.w};
      U8 hh, ll;
      #pragma unroll
      for (int j = 0; j < 8; ++j) { hh.u[j] = f2b(f[j]); ll.u[j] = f2b(f[j] - b2f(hh.u[j])); }
      #pragma unroll
      for (int qt = 0; qt < 2; ++qt) {
        sac[qt][kt] = __builtin_amdgcn_mfma_f32_16x16x32_bf16(hh.v, Qh[qt], sac[qt][kt], 0, 0, 0);
        sac[qt][kt] = __builtin_amdgcn_mfma_f32_16x16x32_bf16(hh.v, Ql[qt], sac[qt][kt], 0, 0, 0);
        sac[qt][kt] = __builtin_amdgcn_mfma_f32_16x16x32_bf16(ll.v, Qh[qt], sac[qt][kt], 0, 0, 0);
      }
    }

    float pj[2][16];
    float scl2[2];
    #pragma unroll
    for (int qt = 0; qt < 2; ++qt) {
      float mc = -3.0e38f;
      #pragma unroll
      for (int kt = 0; kt < 4; ++kt)
        #pragma unroll
        for (int r = 0; r < 4; ++r) {
          float v = sac[qt][kt][r] * cscale;
          pj[qt][kt * 4 + r] = v;
          mc = fmaxf(mc, v);
        }
      mc = fmaxf(mc, __shfl_xor(mc, 16));
      mc = fmaxf(mc, __shfl_xor(mc, 32));
      float mnew = fmaxf(m2[qt], mc);
      float scl = __expf(m2[qt] - mnew);
      float ls = 0.f;
      #pragma unroll
      for (int i = 0; i < 16; ++i) {
        float e = __expf(pj[qt][i] - mnew);
        pj[qt][i] = e;
        ls += e;
      }
      ls += __shfl_xor(ls, 16);
      ls += __shfl_xor(ls, 32);
      l2[qt] = l2[qt] * scl + ls;
      m2[qt] = mnew;
      scl2[qt] = scl;
    }
    #pragma unroll
    for (int dt = 0; dt < 2; ++dt)
      #pragma unroll
      for (int qt = 0; qt < 2; ++qt) {
        #pragma unroll
        for (int r = 0; r < 4; ++r) od[dt][qt][r] *= scl2[qt];
      }

    #pragma unroll
    for (int qt = 0; qt < 2; ++qt) {
      int q32 = qt * 16 + c16;
      unsigned char* pb = &PwB[wave][q32 * 144];
      unsigned sw = (unsigned)((q32 & 7) << 4);
      #pragma unroll
      for (int kt = 0; kt < 4; ++kt)
        #pragma unroll
        for (int rp = 0; rp < 2; ++rp) {
          unsigned pk = (unsigned)f2b(pj[qt][kt * 4 + 2 * rp]) |
                        ((unsigned)f2b(pj[qt][kt * 4 + 2 * rp + 1]) << 16);
          *(unsigned*)&pb[((unsigned)(kt * 32 + kg * 8 + 4 * rp)) ^ sw] = pk;
        }
    }

    #pragma unroll
    for (int kw = 0; kw < 2; ++kw) {
      bf16x8 Pb[2];
      #pragma unroll
      for (int qt = 0; qt < 2; ++qt) {
        int q32 = qt * 16 + c16;
        Pb[qt] = *(const bf16x8*)&PwB[wave][q32 * 144 +
                   (((unsigned)(kw * 64 + kg * 16)) ^ ((unsigned)((q32 & 7) << 4)))];
      }
      #pragma unroll
      for (int dt = 0; dt < 2; ++dt) {
        U8 vh, vl;
        #pragma unroll
        for (int j = 0; j < 8; ++j) {
          float v = Vs[kw * 32 + kg * 8 + j][dt * 16 + c16];
          vh.u[j] = f2b(v);
          vl.u[j] = f2b(v - b2f(vh.u[j]));
        }
        #pragma unroll
        for (int qt = 0; qt < 2; ++qt) {
          od[dt][qt] = __builtin_amdgcn_mfma_f32_16x16x32_bf16(vh.v, Pb[qt], od[dt][qt], 0, 0, 0);
          od[dt][qt] = __builtin_amdgcn_mfma_f32_16x16x32_bf16(vl.v, Pb[qt], od[dt][qt], 0, 0, 0);
        }
      }
    }
  }

  #pragma unroll
  for (int qt = 0; qt < 2; ++qt) {
    float inv = 1.f / l2[qt];
    size_t row = (size_t)bb * 128 + qbase + qt * 16 + c16;
    #pragma unroll
    for (int dt = 0; dt < 2; ++dt)
      #pragma unroll
      for (int r = 0; r < 4; ++r) {
        int colg = h * 32 + dt * 16 + kg * 4 + r;
        O[row * 128 + colg] = Q[row * 128 + colg] + od[dt][qt][r] * inv;
      }
  }
}

// ======================= xg init (= ro_b) =======================
__global__ void xg_init_kernel(float* __restrict__ xg, const float* __restrict__ ro_b) {
  int i = blockIdx.x * 256 + threadIdx.x;
  if (i < BGRAPH * DD) xg[i] = ro_b[0];
}

// ======================= fused classifier + log-softmax head (+ xg passthrough) =======================
__global__ __launch_bounds__(128) void clshead_kernel(
    const float* __restrict__ xg, const float* __restrict__ c1w, const float* __restrict__ c1b,
    const float* __restrict__ c2w, const float* __restrict__ c2b, float* __restrict__ out) {
  int b = blockIdx.x, t = threadIdx.x;
  __shared__ float xr[128];
  __shared__ float hc[128];
  __shared__ float z[10];
  __shared__ float lse_s;
  float xv = xg[b * 128 + t];
  xr[t] = xv;
  out[BGRAPH * 10 + b * 128 + t] = xv;
  __syncthreads();
  float s = c1b[t];
  for (int k = 0; k < 128; ++k) s += xr[k] * c1w[k * 128 + t];
  hc[t] = fmaxf(s, 0.f);
  __syncthreads();
  if (t < 10) {
    float s2 = c2b[t];
    for (int k = 0; k < 128; ++k) s2 += hc[k] * c2w[k * 10 + t];
    z[t] = s2;
  }
  __syncthreads();
  if (t == 0) {
    float mx = z[0];
    for (int c = 1; c < 10; ++c) mx = fmaxf(mx, z[c]);
    float sum = 0.f;
    for (int c = 0; c < 10; ++c) sum += expf(z[c] - mx);
    lse_s = mx + logf(sum);
  }
  __syncthreads();
  if (t < 10) out[b * 10 + t] = z[t] - lse_s;
}

// ======================= launcher =======================
extern "C" void kernel_launch(void* const* d_in, const int* in_sizes, int n_in,
                              void* d_out, int out_size, void* d_ws, size_t ws_size,
                              hipStream_t stream) {
  const float* x       = (const float*)d_in[0];
  const int*   edge    = (const int*)d_in[1];
  const float* enc_w   = (const float*)d_in[2];
  const float* enc_b   = (const float*)d_in[3];
  const float* gconv_w = (const float*)d_in[4];
  const float* gconv_b = (const float*)d_in[5];
  const float* wg1_w   = (const float*)d_in[6];
  const float* wg1_b   = (const float*)d_in[7];
  const float* wg2_w   = (const float*)d_in[8];
  const float* wg2_b   = (const float*)d_in[9];
  const float* pg1_w   = (const float*)d_in[10];
  const float* pg1_b   = (const float*)d_in[11];
  const float* pg2_w   = (const float*)d_in[12];
  const float* pg2_b   = (const float*)d_in[13];
  const float* q_w     = (const float*)d_in[14];
  const float* q_b     = (const float*)d_in[15];
  const float* k_w     = (const float*)d_in[16];
  const float* k_b     = (const float*)d_in[17];
  const float* v_w     = (const float*)d_in[18];
  const float* v_b     = (const float*)d_in[19];
  const float* o_w     = (const float*)d_in[20];
  const float* o_b     = (const float*)d_in[21];
  const float* ro_w    = (const float*)d_in[22];
  const float* ro_b    = (const float*)d_in[23];
  const float* c1_w    = (const float*)d_in[24];
  const float* c1_b    = (const float*)d_in[25];
  const float* c2_w    = (const float*)d_in[26];
  const float* c2_b    = (const float*)d_in[27];

  float* outp = (float*)d_out;

  const size_t S = (size_t)N_NODES * DD;
  float* ws    = (float*)d_ws;
  float* slot0 = ws;
  float* slot1 = ws + S;
  float* slot2 = ws + 2 * S;
  float* slot3 = ws + 3 * S;
  float* smallf = ws + 4 * S;
  int*   cnt  = (int*)smallf;
  int*   fill = cnt + N_NODES;
  int*   rp   = fill + N_NODES;
  int*   col  = rp + N_NODES + 8;
  float* wgt  = (float*)(col + NE);
  float* dinv = wgt + NE;
  float* sc   = dinv + N_NODES;
  float* tb   = sc + 3 * N_NODES;
  float* score = tb + 8 * N_NODES;
  int*   tidx = (int*)(score + N_NODES);
  float* tval = (float*)(tidx + BGRAPH * RATIO_K);
  float* xg   = tval + BGRAPH * RATIO_K;
  unsigned short* wsW = (unsigned short*)(xg + BGRAPH * DD);
  float* aggbuf = (float*)(wsW + 14 * 49152);

  float* t1_0 = tb;
  float* t2_0 = tb + N_NODES;
  float* t1_1 = tb + 2 * N_NODES;
  float* t2_1 = tb + 3 * N_NODES;
  float* t1_2 = tb + 4 * N_NODES;
  float* t2_2 = tb + 5 * N_NODES;
  float* t1_p = tb + 6 * N_NODES;
  float* t2_p = tb + 7 * N_NODES;

  const size_t SP = (size_t)BGRAPH * RATIO_K * DD;
  float* Qm = slot3 + SP;
  float* Om = slot3 + 2 * SP;

  // ---- graph preprocessing ----
  hipMemsetAsync(cnt, 0, N_NODES * sizeof(int), stream);
  hipMemsetAsync(fill, 0, N_NODES * sizeof(int), stream);
  hipMemsetAsync(tb, 0, 8 * N_NODES * sizeof(float), stream);
  count_kernel<<<NE / 256, 256, 0, stream>>>(edge + NE, cnt);
  dinv_kernel<<<N_NODES / 256, 256, 0, stream>>>(cnt, dinv);
  scan_kernel2<<<BGRAPH, 512, 0, stream>>>(cnt, rp);
  scatter_kernel<<<NE / 256, 256, 0, stream>>>(edge, rp, fill, dinv, col, wgt);

  // ---- weight prep ----
  WPtrs wp;
  wp.p[0] = enc_w;
  for (int i = 0; i < 9; ++i) wp.p[1 + i] = gconv_w + (size_t)i * DD * DD;
  wp.p[10] = k_w; wp.p[11] = v_w; wp.p[12] = q_w; wp.p[13] = o_w;
  wprep_all<<<dim3(64, 14), 256, 0, stream>>>(wp, wsW);

  // ---- encoder ----
  mfma_gemm8<1, false, false, false, false, false, false><<<dim3(2, 1024), 256, 0, stream>>>(
      x, wsW, enc_b, nullptr, nullptr, slot0, nullptr,
      nullptr, nullptr, nullptr, nullptr, nullptr, nullptr, nullptr, nullptr);

  const int AGG_GRID = (N_NODES * 32) / 256;
  float* lin[4] = {slot0, slot1, slot2, slot3};
  float* t1s[3] = {t1_0, t1_1, t1_2};
  float* t2s[3] = {t2_0, t2_1, t2_2};

  // ---- layer 0 ----
  agg4_kernel<false><<<AGG_GRID, 256, 0, stream>>>(
      lin[0], rp, col, wgt, dinv, aggbuf, nullptr, nullptr, nullptr, nullptr, nullptr);
  mfma_gemm8<3, true, false, false, true, false, false><<<dim3(2, 1024), 256, 0, stream>>>(
      aggbuf, wsW + 1 * 49152UL, gconv_b, nullptr, nullptr, lin[1], nullptr,
      wg1_w, wg2_w, t1_0, t2_0, nullptr, nullptr, nullptr, nullptr);

  // ---- layers 1,2 with fused prev-layer score ----
  for (int l = 1; l < 3; ++l) {
    agg4_kernel<true><<<AGG_GRID, 256, 0, stream>>>(
        lin[l], rp, col, wgt, dinv, aggbuf,
        t1s[l - 1], t2s[l - 1], wg1_b, wg2_b, sc + (size_t)(l - 1) * N_NODES);
    mfma_gemm8<3, true, false, false, true, false, false><<<dim3(2, 1024), 256, 0, stream>>>(
        aggbuf, wsW + (size_t)(1 + l * 3) * 49152, gconv_b + (size_t)l * 3 * DD,
        nullptr, nullptr, lin[l + 1], nullptr,
        wg1_w, wg2_w, t1s[l], t2s[l], nullptr, nullptr, nullptr, nullptr);
  }

  // ---- layer-2 score ----
  score_kernel<<<N_NODES / 256, 256, 0, stream>>>(t1_2, t2_2, rp, col, wgt, dinv, wg1_b, wg2_b, sc + 2 * (size_t)N_NODES);

  // ---- xf (+ fused pooling dot) ----
  float* xf = slot0;
  xf_kernel<<<(N_NODES * 32) / 256, 256, 0, stream>>>(slot1, slot2, slot3, sc, pg1_w, pg2_w, xf, t1_p, t2_p);

  // ---- K/V aggregation with fused pooling score ----
  agg4_kernel<true><<<AGG_GRID, 256, 0, stream>>>(
      xf, rp, col, wgt, dinv, aggbuf, t1_p, t2_p, pg1_b, pg2_b, score);

  // ---- top-k ----
  topk_kernel<<<BGRAPH, 512, 0, stream>>>(score, tidx, tval);

  // ---- Q GEMM with fused pooled-gather ----
  mfma_gemm8<1, false, false, false, false, true, false><<<dim3(2, 256), 256, 0, stream>>>(
      xf, wsW + 12 * 49152UL, q_b, nullptr, nullptr, Qm, nullptr,
      nullptr, nullptr, nullptr, nullptr, tidx, tval, nullptr, nullptr);

  // ---- fused K+V GEMM ----
  mfma_gemm8<2, false, false, true, false, false, false><<<dim3(2, 1024), 256, 0, stream>>>(
      aggbuf, wsW + 10 * 49152UL, k_b, v_b, nullptr, slot1, slot2,
      nullptr, nullptr, nullptr, nullptr, nullptr, nullptr, nullptr, nullptr);

  // ---- attention ----
  attn_mfma_kernel<<<BGRAPH * NHEAD, 256, 0, stream>>>(Qm, slot1, slot2, Om);

  // ---- xg init; O-GEMM with fused conv1d readout ----
  xg_init_kernel<<<(BGRAPH * DD) / 256, 256, 0, stream>>>(xg, ro_b);
  mfma_gemm8<1, true, true, false, false, false, true><<<dim3(2, 256), 256, 0, stream>>>(
      Om, wsW + 13 * 49152UL, o_b, nullptr, Om, nullptr, nullptr,
      nullptr, nullptr, nullptr, nullptr, nullptr, nullptr, ro_w, xg);

  // ---- fused classifier + head (also writes xg to d_out tail) ----
  clshead_kernel<<<BGRAPH, 128, 0, stream>>>(xg, c1_w, c1_b, c2_w, c2_b, outp);
}